// Round 1
// baseline (567.208 us; speedup 1.0000x reference)
//
#include <hip/hip_runtime.h>

// LocalLayer: B=64, C=3, D=16 units/side, K=8 patch, OUT=1000, P=C*K*K=192, beta=10
// Fused: patches -> a = patches·W^T -> softmax(beta·a) -> pred = z·W -> scatter.
// One block per unit (w,h). Online (shift-free) softmax: with a ~ N(0,0.277^2),
// beta*a stays within exp() fp32 range, so pred = (sum_o e^{beta a_o} W_o) / (sum_o e^{beta a_o}).

#define Dd 16
#define Kk 8
#define Cc 3
#define OUTC 1000
#define Bb 64
#define Pp 192
#define BETA 10.0f
#define OT 64      // o-tile size
#define PPAD 196   // padded row stride for pS/wS (16B-aligned rows, stride%32==4)
#define EPAD 68    // padded row stride for eS

__global__ __launch_bounds__(256, 1)
void local_layer_fused_f32(const float* __restrict__ x,
                           const float* __restrict__ W,
                           float* __restrict__ out) {
  __shared__ float pS[Bb][PPAD];   // patches[b][p]
  __shared__ float wS[OT][PPAD];   // W o-tile, XOR-swizzled rows
  __shared__ float eS[OT][EPAD];   // exp(beta*a) transposed: [o][b]
  __shared__ float lS[Bb];         // softmax denominators

  const int u   = blockIdx.x;
  const int uw  = u >> 4;          // unit row (w)
  const int uh  = u & 15;          // unit col (h)
  const int tid = threadIdx.x;
  const int tx  = tid & 15;
  const int ty  = tid >> 4;

  // ---- stage patches: pS[b][c*64+kh*8+kw] = x[b, c, uw*8+kh, uh*8+kw] ----
  for (int i4 = tid; i4 < Bb * 48; i4 += 256) {
    const int b = i4 / 48, q = i4 - b * 48;
    const int p = q << 2;                       // p%4==0, kw in {0,4} -> contiguous float4
    const int c = p >> 6, kh = (p >> 3) & 7, kw = p & 7;
    const float4 v = *reinterpret_cast<const float4*>(
        x + ((size_t)((b * Cc + c) * 128 + uw * Kk + kh) * 128 + uh * Kk + kw));
    *reinterpret_cast<float4*>(&pS[b][p]) = v;
  }

  float acc[4][12];                 // pred accumulator: 4 b's x 12 p's per thread
#pragma unroll
  for (int i = 0; i < 4; ++i)
#pragma unroll
    for (int k = 0; k < 12; ++k) acc[i][k] = 0.f;
  float lPart[4] = {0.f, 0.f, 0.f, 0.f};

  const float* Wu = W + (size_t)u * OUTC * Pp;
  const int b0  = ty << 2;          // this thread's 4 batch rows
  const int og  = tx << 2;          // this thread's 4 o's in the a-phase
  const int p0  = tx * 12;          // this thread's 12 p's in the pred-phase
  const int swA = (tx & 7) << 2;    // a-phase wS swizzle: (o>>2)&7 == tx&7 for o in [og,og+4)

  for (int o0 = 0; o0 < OUTC; o0 += OT) {
    const int oT = min(OT, OUTC - o0);
    __syncthreads();  // previous iteration's readers of wS/eS are done

    // ---- stage W tile (fully coalesced; rows XOR-swizzled by (o>>2)&7) ----
    for (int i4 = tid; i4 < oT * 48; i4 += 256) {
      const int o = i4 / 48, q = i4 - o * 48;
      const int p  = q << 2;
      const int ps = p ^ (((o >> 2) & 7) << 2);
      const float4 v = *reinterpret_cast<const float4*>(Wu + (size_t)(o0 + o) * Pp + p);
      *reinterpret_cast<float4*>(&wS[o][ps]) = v;
    }
    __syncthreads();

    // ---- a-phase: a[b0..b0+3][og..og+3] = patches · Wrow ----
    {
      float a[4][4];
#pragma unroll
      for (int i = 0; i < 4; ++i)
#pragma unroll
        for (int j = 0; j < 4; ++j) a[i][j] = 0.f;

#pragma unroll 4
      for (int p = 0; p < Pp; p += 4) {
        float4 pa[4], wb[4];
#pragma unroll
        for (int i = 0; i < 4; ++i)
          pa[i] = *reinterpret_cast<const float4*>(&pS[b0 + i][p]);
#pragma unroll
        for (int j = 0; j < 4; ++j)
          wb[j] = *reinterpret_cast<const float4*>(&wS[og + j][p ^ swA]);
#pragma unroll
        for (int i = 0; i < 4; ++i)
#pragma unroll
          for (int j = 0; j < 4; ++j)
            a[i][j] += pa[i].x * wb[j].x + pa[i].y * wb[j].y +
                       pa[i].z * wb[j].z + pa[i].w * wb[j].w;
      }

      float e[4][4];
#pragma unroll
      for (int j = 0; j < 4; ++j) {
        const bool valid = (o0 + og + j) < OUTC;
#pragma unroll
        for (int i = 0; i < 4; ++i)
          e[i][j] = valid ? __expf(BETA * a[i][j]) : 0.f;
      }
#pragma unroll
      for (int j = 0; j < 4; ++j) {
        float4 e4 = make_float4(e[0][j], e[1][j], e[2][j], e[3][j]);
        *reinterpret_cast<float4*>(&eS[og + j][b0]) = e4;
      }
#pragma unroll
      for (int i = 0; i < 4; ++i)
        lPart[i] += e[i][0] + e[i][1] + e[i][2] + e[i][3];
    }
    __syncthreads();

    // ---- pred-phase: acc[b][p] += sum_o eS[o][b] * wS[o][p] ----
#pragma unroll 2
    for (int o = 0; o < oT; ++o) {
      const int sw = ((o >> 2) & 7) << 2;
      const float4 e4 = *reinterpret_cast<const float4*>(&eS[o][b0]);
      const float4 w0 = *reinterpret_cast<const float4*>(&wS[o][(p0)      ^ sw]);
      const float4 w1 = *reinterpret_cast<const float4*>(&wS[o][(p0 + 4)  ^ sw]);
      const float4 w2 = *reinterpret_cast<const float4*>(&wS[o][(p0 + 8)  ^ sw]);
      const float ev[4] = {e4.x, e4.y, e4.z, e4.w};
#pragma unroll
      for (int i = 0; i < 4; ++i) {
        const float ei = ev[i];
        acc[i][0]  += ei * w0.x; acc[i][1]  += ei * w0.y;
        acc[i][2]  += ei * w0.z; acc[i][3]  += ei * w0.w;
        acc[i][4]  += ei * w1.x; acc[i][5]  += ei * w1.y;
        acc[i][6]  += ei * w1.z; acc[i][7]  += ei * w1.w;
        acc[i][8]  += ei * w2.x; acc[i][9]  += ei * w2.y;
        acc[i][10] += ei * w2.z; acc[i][11] += ei * w2.w;
      }
    }
  }

  // ---- reduce softmax denominators across the 16 tx-threads sharing each b ----
#pragma unroll
  for (int i = 0; i < 4; ++i) {
    float v = lPart[i];
    v += __shfl_xor(v, 1, 16);
    v += __shfl_xor(v, 2, 16);
    v += __shfl_xor(v, 4, 16);
    v += __shfl_xor(v, 8, 16);
    if (tx == 0) lS[b0 + i] = v;
  }
  __syncthreads();

  // ---- epilogue: out[b, c, uw*8+kh, uh*8+kw] = acc / l ----
#pragma unroll
  for (int i = 0; i < 4; ++i) {
    const int b = b0 + i;
    const float inv = 1.0f / lS[b];
#pragma unroll
    for (int g = 0; g < 3; ++g) {
      const int p = p0 + 4 * g;                 // 4 consecutive p share (c,kh); kw in {0,4}
      const int c = p >> 6, kh = (p >> 3) & 7, kw = p & 7;
      float4 v;
      v.x = acc[i][4 * g + 0] * inv;
      v.y = acc[i][4 * g + 1] * inv;
      v.z = acc[i][4 * g + 2] * inv;
      v.w = acc[i][4 * g + 3] * inv;
      *reinterpret_cast<float4*>(
          out + ((size_t)((b * Cc + c) * 128 + uw * Kk + kh) * 128 + uh * Kk + kw)) = v;
    }
  }
}

extern "C" void kernel_launch(void* const* d_in, const int* in_sizes, int n_in,
                              void* d_out, int out_size, void* d_ws, size_t ws_size,
                              hipStream_t stream) {
  const float* x = (const float*)d_in[0];
  const float* W = (const float*)d_in[1];
  float* out = (float*)d_out;
  hipLaunchKernelGGL(local_layer_fused_f32, dim3(Dd * Dd), dim3(256), 0, stream,
                     x, W, out);
}

// Round 2
// 292.453 us; speedup vs baseline: 1.9395x; 1.9395x over previous
//
#include <hip/hip_runtime.h>

// LocalLayer fused via MFMA: a = patches·W^T (hi/lo split bf16, 3 passes),
// e = exp(beta*a) (shift-free softmax), pred = e·W / sum(e) (plain bf16).
// One block per unit, 512 threads = 8 waves (2 m-halves x 4 o-quarters).

#define Dd 16
#define OUTC 1000
#define Pp 192
#define Bb 64
#define OT 64
#define NT 16
#define THREADS 512
#define BETA 10.0f

typedef __attribute__((ext_vector_type(8))) short short8;
typedef __attribute__((ext_vector_type(4))) float f32x4;

#define MFMA(a, b, c) __builtin_amdgcn_mfma_f32_16x16x32_bf16((a), (b), (c), 0, 0, 0)

__device__ __forceinline__ unsigned f2bf(float f) {  // RNE f32->bf16 bits
  unsigned u = __float_as_uint(f);
  return (u + 0x7fffu + ((u >> 16) & 1u)) >> 16;
}

// byte addrs, XOR-swizzled 16B blocks (keeps all frag reads ~2-way = free)
__device__ __forceinline__ int paddr(int b, int p) {   // pH/pL [64][192] bf16
  return b * 384 + ((((p) >> 3) ^ (b & 7)) << 4) + ((p) & 7) * 2;
}
__device__ __forceinline__ int waddr(int o, int p) {   // wH/wL [64][192] bf16
  int f = (o & 7) ^ ((o >> 3) & 3);                    // also spreads m2 k-gathers
  return o * 384 + ((((p) >> 3) ^ f) << 4) + ((p) & 7) * 2;
}
__device__ __forceinline__ int eaddr(int b, int o) {   // eS [64][64] bf16
  return b * 128 + ((((o) >> 3) ^ (b & 7)) << 4) + ((o) & 7) * 2;
}

__device__ __forceinline__ void cvt_hilo4(const float4 v, uint2& hi2, uint2& lo2) {
  unsigned h0 = f2bf(v.x), h1 = f2bf(v.y), h2 = f2bf(v.z), h3 = f2bf(v.w);
  float l0 = v.x - __uint_as_float(h0 << 16);
  float l1 = v.y - __uint_as_float(h1 << 16);
  float l2 = v.z - __uint_as_float(h2 << 16);
  float l3 = v.w - __uint_as_float(h3 << 16);
  unsigned g0 = f2bf(l0), g1 = f2bf(l1), g2 = f2bf(l2), g3 = f2bf(l3);
  hi2 = make_uint2(h0 | (h1 << 16), h2 | (h3 << 16));
  lo2 = make_uint2(g0 | (g1 << 16), g2 | (g3 << 16));
}

__global__ __launch_bounds__(THREADS, 2)
void local_layer_mfma(const float* __restrict__ x,
                      const float* __restrict__ W,
                      float* __restrict__ out) {
  __shared__ unsigned short pH[Bb * Pp];
  __shared__ unsigned short pL[Bb * Pp];
  __shared__ unsigned short wHs[OT * Pp];
  __shared__ unsigned short wLs[OT * Pp];
  __shared__ unsigned short eSs[Bb * OT];
  __shared__ float lS[Bb];

  char* pHc = (char*)pH; char* pLc = (char*)pL;
  char* wHc = (char*)wHs; char* wLc = (char*)wLs;
  char* eSc = (char*)eSs;

  const int u = blockIdx.x, uw = u >> 4, uh = u & 15;
  const int tid = threadIdx.x;
  const int wv = tid >> 6, lane = tid & 63;
  const int lr = lane & 15, lg = lane >> 4;
  const int mw = wv & 1;            // m-half: rows 32*mw .. +31
  const int ow = wv >> 1;           // 0..3: m1 o-16 group / m2 p-48 group
  const int bB = 32 * mw;

  const float* Wu = W + (size_t)u * (OUTC * Pp);

  if (tid < Bb) lS[tid] = 0.f;

  // ---- prefetch W tile 0 into regs ----
  float4 R[6];
#pragma unroll
  for (int k = 0; k < 6; ++k) {
    int i4 = tid + THREADS * k;
    int o = i4 / 48, p = (i4 % 48) * 4;
    R[k] = *reinterpret_cast<const float4*>(Wu + o * Pp + p);
  }

  // ---- stage patches -> pH/pL (hi/lo bf16) ----
  for (int i4 = tid; i4 < Bb * 48; i4 += THREADS) {
    int b = i4 / 48, q = i4 - b * 48, p = q * 4;
    int c = p >> 6, kh = (p >> 3) & 7, kw = p & 7;
    float4 v = *reinterpret_cast<const float4*>(
        x + ((size_t)((b * 3 + c) * 128 + uw * 8 + kh) * 128 + uh * 8 + kw));
    uint2 hi2, lo2;
    cvt_hilo4(v, hi2, lo2);
    *reinterpret_cast<uint2*>(pHc + paddr(b, p)) = hi2;
    *reinterpret_cast<uint2*>(pLc + paddr(b, p)) = lo2;
  }

  // ---- convert+write W tile 0 ----
#pragma unroll
  for (int k = 0; k < 6; ++k) {
    int i4 = tid + THREADS * k;
    int o = i4 / 48, p = (i4 % 48) * 4;
    uint2 hi2, lo2;
    cvt_hilo4(R[k], hi2, lo2);
    *reinterpret_cast<uint2*>(wHc + waddr(o, p)) = hi2;
    *reinterpret_cast<uint2*>(wLc + waddr(o, p)) = lo2;
  }
  __syncthreads();   // pS + tile0 visible

  // ---- hoist patch A-frags (tile-invariant): rows bB+16h+lr, k = 32ks+8lg ----
  short8 pa_h[2][6], pa_l[2][6];
#pragma unroll
  for (int h = 0; h < 2; ++h)
#pragma unroll
    for (int ks = 0; ks < 6; ++ks) {
      pa_h[h][ks] = *reinterpret_cast<const short8*>(pHc + paddr(bB + 16 * h + lr, 32 * ks + 8 * lg));
      pa_l[h][ks] = *reinterpret_cast<const short8*>(pLc + paddr(bB + 16 * h + lr, 32 * ks + 8 * lg));
    }

  f32x4 pacc[2][3];
#pragma unroll
  for (int h = 0; h < 2; ++h)
#pragma unroll
    for (int f = 0; f < 3; ++f) pacc[h][f] = (f32x4){0.f, 0.f, 0.f, 0.f};
  float lPartA[2][4] = {{0.f, 0.f, 0.f, 0.f}, {0.f, 0.f, 0.f, 0.f}};

  for (int t = 0; t < NT; ++t) {
    // ---- issue async loads for tile t+1 (consumed after m2) ----
    if (t + 1 < NT) {
#pragma unroll
      for (int k = 0; k < 6; ++k) {
        int i4 = tid + THREADS * k;
        int o = i4 / 48, p = (i4 % 48) * 4;
        int o_g = (t + 1) * OT + o;
        R[k] = (o_g < OUTC)
                   ? *reinterpret_cast<const float4*>(Wu + (size_t)o_g * Pp + p)
                   : make_float4(0.f, 0.f, 0.f, 0.f);
      }
    }

    // ---- m1: a[16h rows][16ow o-cols] over K=192, hi/lo 3 passes ----
    f32x4 acc[2] = {(f32x4){0.f, 0.f, 0.f, 0.f}, (f32x4){0.f, 0.f, 0.f, 0.f}};
#pragma unroll
    for (int ks = 0; ks < 6; ++ks) {
      short8 wbh = *reinterpret_cast<const short8*>(wHc + waddr(16 * ow + lr, 32 * ks + 8 * lg));
      short8 wbl = *reinterpret_cast<const short8*>(wLc + waddr(16 * ow + lr, 32 * ks + 8 * lg));
#pragma unroll
      for (int h = 0; h < 2; ++h) {
        acc[h] = MFMA(pa_h[h][ks], wbh, acc[h]);
        acc[h] = MFMA(pa_h[h][ks], wbl, acc[h]);
        acc[h] = MFMA(pa_l[h][ks], wbh, acc[h]);
      }
    }

    // ---- e = exp(beta*a), zero invalid o, write eS, accumulate lPart ----
    {
      const int o_g = t * OT + 16 * ow + lr;
      const bool valid = (o_g < OUTC);
#pragma unroll
      for (int h = 0; h < 2; ++h)
#pragma unroll
        for (int j = 0; j < 4; ++j) {
          float e = valid ? __expf(BETA * acc[h][j]) : 0.f;
          lPartA[h][j] += e;
          *reinterpret_cast<unsigned short*>(
              eSc + eaddr(bB + 16 * h + 4 * lg + j, 16 * ow + lr)) =
              (unsigned short)f2bf(e);
        }
    }
    __syncthreads();   // eS complete (m2 A-frags need all waves' e)

    // ---- m2: pred[b][p] += e·W  (A = eS rows, B = wH k-gather) ----
    short8 ea[2][2];
#pragma unroll
    for (int h = 0; h < 2; ++h)
#pragma unroll
      for (int ks2 = 0; ks2 < 2; ++ks2)
        ea[h][ks2] = *reinterpret_cast<const short8*>(
            eSc + eaddr(bB + 16 * h + lr, 32 * ks2 + 8 * lg));

#pragma unroll
    for (int f = 0; f < 3; ++f) {
      const int p = 48 * ow + 16 * f + lr;
#pragma unroll
      for (int ks2 = 0; ks2 < 2; ++ks2) {
        short8 wb;
#pragma unroll
        for (int e8 = 0; e8 < 8; ++e8)
          wb[e8] = *reinterpret_cast<const short*>(
              wHc + waddr(32 * ks2 + 8 * lg + e8, p));
#pragma unroll
        for (int h = 0; h < 2; ++h)
          pacc[h][f] = MFMA(ea[h][ks2], wb, pacc[h][f]);
      }
    }
    __syncthreads();   // m2 done reading wH/eS before overwrite

    // ---- convert+write tile t+1 (R loaded at top of this iteration) ----
    if (t + 1 < NT) {
#pragma unroll
      for (int k = 0; k < 6; ++k) {
        int i4 = tid + THREADS * k;
        int o = i4 / 48, p = (i4 % 48) * 4;
        uint2 hi2, lo2;
        cvt_hilo4(R[k], hi2, lo2);
        *reinterpret_cast<uint2*>(wHc + waddr(o, p)) = hi2;
        *reinterpret_cast<uint2*>(wLc + waddr(o, p)) = lo2;
      }
      __syncthreads();  // tile t+1 visible for next m1
    }
  }

  // ---- softmax denominators: reduce lPart over the 16 lr lanes ----
#pragma unroll
  for (int h = 0; h < 2; ++h)
#pragma unroll
    for (int j = 0; j < 4; ++j) {
      float v = lPartA[h][j];
      v += __shfl_xor(v, 1, 16);
      v += __shfl_xor(v, 2, 16);
      v += __shfl_xor(v, 4, 16);
      v += __shfl_xor(v, 8, 16);
      if (lr == 0) atomicAdd(&lS[bB + 16 * h + 4 * lg + j], v);
    }
  __syncthreads();

  // ---- epilogue: out = pacc / l, scatter to image layout ----
#pragma unroll
  for (int h = 0; h < 2; ++h) {
    float inv[4];
#pragma unroll
    for (int j = 0; j < 4; ++j) inv[j] = 1.f / lS[bB + 16 * h + 4 * lg + j];
#pragma unroll
    for (int f = 0; f < 3; ++f) {
      const int p = 48 * ow + 16 * f + lr;
      const int c = p >> 6, kh = (p >> 3) & 7, kw = p & 7;
#pragma unroll
      for (int j = 0; j < 4; ++j) {
        const int b = bB + 16 * h + 4 * lg + j;
        out[((size_t)((b * 3 + c) * 128 + uw * 8 + kh)) * 128 + uh * 8 + kw] =
            pacc[h][f][j] * inv[j];
      }
    }
  }
}

extern "C" void kernel_launch(void* const* d_in, const int* in_sizes, int n_in,
                              void* d_out, int out_size, void* d_ws, size_t ws_size,
                              hipStream_t stream) {
  const float* x = (const float*)d_in[0];
  const float* W = (const float*)d_in[1];
  float* out = (float*)d_out;
  hipLaunchKernelGGL(local_layer_mfma, dim3(Dd * Dd), dim3(THREADS), 0, stream,
                     x, W, out);
}